// Round 1
// baseline (170.890 us; speedup 1.0000x reference)
//
#include <hip/hip_runtime.h>
#include <hip/hip_bf16.h>
#include <stdint.h>

typedef __attribute__((ext_vector_type(8))) __bf16 bf16x8;
typedef __attribute__((ext_vector_type(4))) float f32x4;

constexpr int Bn = 4096;   // batch
constexpr int Dd = 1024;   // feature dim
constexpr int Cc = 1000;   // classes

__device__ __forceinline__ float wsum(float v) {
#pragma unroll
  for (int m = 32; m >= 1; m >>= 1) v += __shfl_xor(v, m);
  return v;
}
__device__ __forceinline__ float wmax(float v) {
#pragma unroll
  for (int m = 32; m >= 1; m >>= 1) v = fmaxf(v, __shfl_xor(v, m));
  return v;
}

// ---- zero/init scratch (ws is re-poisoned 0xAA before every call) ----
__global__ void init_kernel(float* __restrict__ total, int* __restrict__ first_occ) {
  int i = blockIdx.x * blockDim.x + threadIdx.x;
  if (i < Bn) total[i] = 0.0f;
  if (i < Cc) first_occ[i] = 0x7fffffff;
}

// ---- first occurrence of each class ----
__global__ void firstocc_kernel(const int* __restrict__ y, int* __restrict__ first_occ) {
  int i = blockIdx.x * blockDim.x + threadIdx.x;
  if (i < Bn) atomicMin(&first_occ[y[i]], i);
}

// ---- L2-normalize rows of x, emit bf16 ----
__global__ void normalize_kernel(const float* __restrict__ x, unsigned short* __restrict__ xn) {
  int row = blockIdx.x;
  int t = threadIdx.x;                      // 256 threads, 4 floats each
  const float4* xr = (const float4*)(x + (size_t)row * Dd);
  float4 v = xr[t];
  float ss = v.x * v.x + v.y * v.y + v.z * v.z + v.w * v.w;
  ss = wsum(ss);
  __shared__ float red[4];
  if ((t & 63) == 0) red[t >> 6] = ss;
  __syncthreads();
  float inv = 1.0f / fmaxf(sqrtf(red[0] + red[1] + red[2] + red[3]), 1e-8f);
  float f[4] = {v.x * inv, v.y * inv, v.z * inv, v.w * inv};
  ushort4 o;
  unsigned short* op = (unsigned short*)&o;
#pragma unroll
  for (int k = 0; k < 4; k++) {            // f32 -> bf16 round-to-nearest-even
    unsigned u = __float_as_uint(f[k]);
    u += 0x7fffu + ((u >> 16) & 1u);
    op[k] = (unsigned short)(u >> 16);
  }
  ((ushort4*)(xn + (size_t)row * Dd))[t] = o;
}

// ---- S[i, j_star[i]] directly (one block per row) ----
__global__ void posdot_kernel(const unsigned short* __restrict__ xn, const int* __restrict__ y,
                              const int* __restrict__ first_occ, float* __restrict__ posdot) {
  int i = blockIdx.x;
  int t = threadIdx.x;
  int j = first_occ[y[i]];
  const ushort4* a = (const ushort4*)(xn + (size_t)i * Dd);
  const ushort4* b = (const ushort4*)(xn + (size_t)j * Dd);
  ushort4 av = a[t], bv = b[t];
  float s = 0.f;
  s += __uint_as_float((unsigned)av.x << 16) * __uint_as_float((unsigned)bv.x << 16);
  s += __uint_as_float((unsigned)av.y << 16) * __uint_as_float((unsigned)bv.y << 16);
  s += __uint_as_float((unsigned)av.z << 16) * __uint_as_float((unsigned)bv.z << 16);
  s += __uint_as_float((unsigned)av.w << 16) * __uint_as_float((unsigned)bv.w << 16);
  s = wsum(s);
  __shared__ float red[4];
  if ((t & 63) == 0) red[t >> 6] = s;
  __syncthreads();
  if (t == 0) posdot[i] = red[0] + red[1] + red[2] + red[3];
}

// ---- cross-entropy per row: celogp[i] = -(logit_y - logsumexp) ----
__global__ void ce_kernel(const float* __restrict__ data, const int* __restrict__ y,
                          float* __restrict__ celogp) {
  int i = blockIdx.x;
  int t = threadIdx.x;
  const float* row = data + (size_t)i * Cc;
  float m = -1e30f;
  for (int c = t; c < Cc; c += 256) m = fmaxf(m, row[c]);
  m = wmax(m);
  __shared__ float redm[4];
  __shared__ float reds[4];
  if ((t & 63) == 0) redm[t >> 6] = m;
  __syncthreads();
  m = fmaxf(fmaxf(redm[0], redm[1]), fmaxf(redm[2], redm[3]));
  float s = 0.f;
  for (int c = t; c < Cc; c += 256) s += __expf(row[c] - m);
  s = wsum(s);
  if ((t & 63) == 0) reds[t >> 6] = s;
  __syncthreads();
  if (t == 0) {
    float tot = reds[0] + reds[1] + reds[2] + reds[3];
    celogp[i] = -(row[y[i]] - m - logf(tot));
  }
}

// ---- async global->LDS, width 16 ----
__device__ __forceinline__ void gload16(const void* g, void* l) {
  __builtin_amdgcn_global_load_lds((const __attribute__((address_space(1))) void*)g,
                                   (__attribute__((address_space(3))) void*)l, 16, 0, 0);
}

// ---- fused S = xn @ xn^T tile GEMM with exp+rowsum epilogue ----
// 128x128 tile, 4 waves (2x2 of 64x64), BK=32, mfma_f32_16x16x32_bf16.
// LDS layout [kg][row][8] bf16 so global_load_lds's linear lane order == fragment order,
// and ds_read_b128 of a fragment hits consecutive 16B slots (conflict-free).
__global__ __launch_bounds__(256, 2) void gemm_expsum_kernel(const __bf16* __restrict__ xn,
                                                             float* __restrict__ total) {
  constexpr int BM = 128, BK = 32;
  __shared__ __bf16 ldsA[BM * BK];
  __shared__ __bf16 ldsB[BM * BK];
  int t = threadIdx.x;
  int lane = t & 63;
  int wave = t >> 6;
  int wr = wave >> 1, wc = wave & 1;
  int arow0 = blockIdx.x * BM;
  int brow0 = blockIdx.y * BM;
  f32x4 acc[4][4] = {};
  int kg = lane >> 4, fr = lane & 15;
  int aidx = (kg * 128 + wr * 64 + fr) * 8;
  int bidx = (kg * 128 + wc * 64 + fr) * 8;
  for (int k0 = 0; k0 < Dd; k0 += BK) {
    __syncthreads();
#pragma unroll
    for (int s = 0; s < 2; s++) {
      int tt = s * 256 + t;
      int skg = tt >> 7, srow = tt & 127;   // tt = skg*128 + srow == linear LDS slot
      gload16(xn + (size_t)(arow0 + srow) * Dd + k0 + skg * 8, &ldsA[(tt & ~63) * 8]);
      gload16(xn + (size_t)(brow0 + srow) * Dd + k0 + skg * 8, &ldsB[(tt & ~63) * 8]);
    }
    __syncthreads();
    bf16x8 af[4], bfr[4];
#pragma unroll
    for (int mi = 0; mi < 4; mi++) af[mi] = *(const bf16x8*)&ldsA[aidx + mi * 16 * 8];
#pragma unroll
    for (int nj = 0; nj < 4; nj++) bfr[nj] = *(const bf16x8*)&ldsB[bidx + nj * 16 * 8];
#pragma unroll
    for (int mi = 0; mi < 4; mi++)
#pragma unroll
      for (int nj = 0; nj < 4; nj++)
        acc[mi][nj] = __builtin_amdgcn_mfma_f32_16x16x32_bf16(af[mi], bfr[nj], acc[mi][nj], 0, 0, 0);
  }
  // epilogue: total[row] += sum_cols exp(2*S) ; exp(2s)=exp2(s*2*log2(e))
  const float c2 = 2.885390081777927f;
  int rgrp = lane >> 4;
#pragma unroll
  for (int mi = 0; mi < 4; mi++) {
#pragma unroll
    for (int reg = 0; reg < 4; reg++) {
      float s = 0.f;
#pragma unroll
      for (int nj = 0; nj < 4; nj++) s += exp2f(acc[mi][nj][reg] * c2);
#pragma unroll
      for (int m = 1; m <= 8; m <<= 1) s += __shfl_xor(s, m);  // reduce over 16 col-lanes
      if ((lane & 15) == 0) {
        int row = arow0 + wr * 64 + mi * 16 + rgrp * 4 + reg;
        atomicAdd(&total[row], s);
      }
    }
  }
}

// ---- final reduction: loss_feature = mean(log(total) - 2*posdot); combine ----
__global__ void finalize_kernel(const float* __restrict__ total, const float* __restrict__ posdot,
                                const float* __restrict__ celogp, float* __restrict__ out) {
  int t = threadIdx.x;  // 1024 threads
  float fs = 0.f, cs = 0.f;
  for (int i = t; i < Bn; i += 1024) {
    fs += logf(total[i]) - 2.0f * posdot[i];
    cs += celogp[i];
  }
  fs = wsum(fs);
  cs = wsum(cs);
  __shared__ float rf[16], rc[16];
  if ((t & 63) == 0) { rf[t >> 6] = fs; rc[t >> 6] = cs; }
  __syncthreads();
  if (t == 0) {
    float lf = 0.f, la = 0.f;
#pragma unroll
    for (int w = 0; w < 16; w++) { lf += rf[w]; la += rc[w]; }
    lf /= (float)Bn;
    la /= (float)Bn;
    out[0] = la + 0.05f * lf;
    out[1] = la;
    out[2] = lf;
  }
}

extern "C" void kernel_launch(void* const* d_in, const int* in_sizes, int n_in,
                              void* d_out, int out_size, void* d_ws, size_t ws_size,
                              hipStream_t stream) {
  const float* data = (const float*)d_in[0];
  const float* x = (const float*)d_in[1];
  const int* y = (const int*)d_in[2];
  char* ws = (char*)d_ws;
  unsigned short* xn = (unsigned short*)ws;                       // 8 MB bf16
  float* total = (float*)(ws + (size_t)8 * 1024 * 1024);          // 16 KB
  float* posdot = total + Bn;                                     // 16 KB
  float* celogp = posdot + Bn;                                    // 16 KB
  int* first_occ = (int*)(celogp + Bn);                           // 4 KB
  float* out = (float*)d_out;

  hipLaunchKernelGGL(init_kernel, dim3(16), dim3(256), 0, stream, total, first_occ);
  hipLaunchKernelGGL(normalize_kernel, dim3(Bn), dim3(256), 0, stream, x, xn);
  hipLaunchKernelGGL(firstocc_kernel, dim3(16), dim3(256), 0, stream, y, first_occ);
  hipLaunchKernelGGL(posdot_kernel, dim3(Bn), dim3(256), 0, stream, xn, y, first_occ, posdot);
  hipLaunchKernelGGL(gemm_expsum_kernel, dim3(32, 32), dim3(256), 0, stream, (const __bf16*)xn, total);
  hipLaunchKernelGGL(ce_kernel, dim3(Bn), dim3(256), 0, stream, data, y, celogp);
  hipLaunchKernelGGL(finalize_kernel, dim3(1), dim3(1024), 0, stream, total, posdot, celogp, out);
}

// Round 3
// 120.143 us; speedup vs baseline: 1.4224x; 1.4224x over previous
//
#include <hip/hip_runtime.h>
#include <hip/hip_bf16.h>
#include <stdint.h>

typedef __attribute__((ext_vector_type(8))) __bf16 bf16x8;
typedef __attribute__((ext_vector_type(4))) float f32x4;

constexpr int Bn = 4096;   // batch
constexpr int Dd = 1024;   // feature dim
constexpr int Cc = 1000;   // classes
constexpr int NPANEL = 32;              // Bn / 128
constexpr int PANEL_ELEMS = 128 * Dd;   // 131072 elems per 128-row panel
constexpr int NT = Dd / 32;             // 32 K-steps of BK=32

__device__ __forceinline__ float wsum(float v) {
#pragma unroll
  for (int m = 32; m >= 1; m >>= 1) v += __shfl_xor(v, m);
  return v;
}
__device__ __forceinline__ float wmax(float v) {
#pragma unroll
  for (int m = 32; m >= 1; m >>= 1) v = fmaxf(v, __shfl_xor(v, m));
  return v;
}

// ---- fused: normalize rows of x into blocked-bf16 xnt + CE rows + scratch init ----
// blocks [0, Bn): normalize row b; also total[b]=0, first_occ init.
// blocks [Bn, 2Bn): cross-entropy for row b-Bn.
// Blocked layout: elem (row r, k) at  (r>>7)*131072 + (k>>5)*4096 + ((k>>3)&3)*1024 + (r&127)*8 + (k&7)
// so each 128x32 K-step tile is one contiguous 8KB block, image = [kg][row][8].
__global__ void prep_kernel(const float* __restrict__ data, const float* __restrict__ x,
                            const int* __restrict__ y, unsigned short* __restrict__ xnt,
                            float* __restrict__ celogp, float* __restrict__ total,
                            int* __restrict__ first_occ) {
  __shared__ float red[4];
  __shared__ float red2[4];
  int b = blockIdx.x;
  int t = threadIdx.x;
  if (b < Bn) {
    if (t == 0) total[b] = 0.0f;
    if (t == 1 && b < Cc) first_occ[b] = 0x7fffffff;
    const float4* xr = (const float4*)(x + (size_t)b * Dd);
    float4 v = xr[t];                       // 256 threads * 4 floats
    float ss = v.x * v.x + v.y * v.y + v.z * v.z + v.w * v.w;
    ss = wsum(ss);
    if ((t & 63) == 0) red[t >> 6] = ss;
    __syncthreads();
    float inv = 1.0f / fmaxf(sqrtf(red[0] + red[1] + red[2] + red[3]), 1e-8f);
    float f[4] = {v.x * inv, v.y * inv, v.z * inv, v.w * inv};
    ushort4 o;
    unsigned short* op = (unsigned short*)&o;
#pragma unroll
    for (int k = 0; k < 4; k++) {          // f32 -> bf16 RNE
      unsigned u = __float_as_uint(f[k]);
      u += 0x7fffu + ((u >> 16) & 1u);
      op[k] = (unsigned short)(u >> 16);
    }
    int p = b >> 7, rl = b & 127;
    int d = t * 4;                          // global k of first elem
    int kt = d >> 5, kg = (d >> 3) & 3, e = d & 7;  // e in {0,4}
    *(ushort4*)(xnt + (size_t)p * PANEL_ELEMS + kt * 4096 + kg * 1024 + rl * 8 + e) = o;
  } else {
    int i = b - Bn;
    const float* row = data + (size_t)i * Cc;
    float m = -1e30f;
    for (int c = t; c < Cc; c += 256) m = fmaxf(m, row[c]);
    m = wmax(m);
    if ((t & 63) == 0) red[t >> 6] = m;
    __syncthreads();
    m = fmaxf(fmaxf(red[0], red[1]), fmaxf(red[2], red[3]));
    float s = 0.f;
    for (int c = t; c < Cc; c += 256) s += __expf(row[c] - m);
    s = wsum(s);
    if ((t & 63) == 0) red2[t >> 6] = s;
    __syncthreads();
    if (t == 0) {
      float tot = red2[0] + red2[1] + red2[2] + red2[3];
      celogp[i] = -(row[y[i]] - m - logf(tot));
    }
  }
}

// ---- first occurrence of each class ----
__global__ void firstocc_kernel(const int* __restrict__ y, int* __restrict__ first_occ) {
  int i = blockIdx.x * blockDim.x + threadIdx.x;
  if (i < Bn) atomicMin(&first_occ[y[i]], i);
}

// ---- async global->LDS, width 16 ----
__device__ __forceinline__ void gload16(const void* g, void* l) {
  __builtin_amdgcn_global_load_lds((const __attribute__((address_space(1))) void*)g,
                                   (__attribute__((address_space(3))) void*)l, 16, 0, 0);
}

// ---- fused symmetric S = xn @ xn^T, upper-triangle tiles only ----
// 128x128 tile, 4 waves (2x2 of 64x64), BK=32, mfma_f32_16x16x32_bf16, dbuf LDS.
// Epilogue: exp(2S) row-sums (+ col-sums for off-diag tiles, S symmetric) into total[],
// and posdot[c] = S[jstar[c], c] (jstar[c] <= c -> lies in exactly one computed tile).
__global__ __launch_bounds__(256, 2) void gemm_expsum_kernel(
    const __bf16* __restrict__ xnt, const int* __restrict__ y,
    const int* __restrict__ first_occ, float* __restrict__ total,
    float* __restrict__ posdot) {
  __shared__ __align__(16) __bf16 lds[2][2][4096];   // [buf][A/B][kg*1024 + row*8 + e]
  int t = threadIdx.x, lane = t & 63, wave = t >> 6;
  int wr = wave >> 1, wc = wave & 1;
  // blockIdx -> upper-triangle (bi <= bj)
  int bi = 0, rem = blockIdx.x;
  while (rem >= NPANEL - bi) { rem -= NPANEL - bi; ++bi; }
  int bj = bi + rem;
  const __bf16* pa = xnt + (size_t)bi * PANEL_ELEMS;
  const __bf16* pb = xnt + (size_t)bj * PANEL_ELEMS;
  int kg = lane >> 4, fr = lane & 15;
  int aoff = kg * 1024 + (wr * 64 + fr) * 8;
  int boff = kg * 1024 + (wc * 64 + fr) * 8;
  f32x4 acc[4][4] = {};

#define STAGE(buf, kt)                                                        \
  do {                                                                        \
    const __bf16* ta = pa + (kt) * 4096;                                      \
    const __bf16* tb = pb + (kt) * 4096;                                      \
    _Pragma("unroll") for (int r = 0; r < 2; ++r) {                           \
      int slot = r * 256 + t;                                                 \
      int ub = (r * 256 + (t & ~63)) * 8; /* wave-uniform dest base */        \
      gload16(ta + slot * 8, &lds[buf][0][ub]);                               \
      gload16(tb + slot * 8, &lds[buf][1][ub]);                               \
    }                                                                         \
  } while (0)

  STAGE(0, 0);
  __syncthreads();
  int cur = 0;
  for (int kt = 0; kt < NT; ++kt) {
    if (kt + 1 < NT) STAGE(cur ^ 1, kt + 1);   // prefetch next tile into other buffer
    bf16x8 af[4], bg[4];
#pragma unroll
    for (int mi = 0; mi < 4; mi++) af[mi] = *(const bf16x8*)&lds[cur][0][aoff + mi * 128];
#pragma unroll
    for (int nj = 0; nj < 4; nj++) bg[nj] = *(const bf16x8*)&lds[cur][1][boff + nj * 128];
#pragma unroll
    for (int mi = 0; mi < 4; mi++)
#pragma unroll
      for (int nj = 0; nj < 4; nj++)
        acc[mi][nj] = __builtin_amdgcn_mfma_f32_16x16x32_bf16(af[mi], bg[nj], acc[mi][nj], 0, 0, 0);
    __syncthreads();   // drains staging vmcnt + frag lgkm; buffers swap
    cur ^= 1;
  }
#undef STAGE

  // epilogue: exp(2s) = exp2(s * 2*log2(e))
  const float c2 = 2.885390081777927f;
  int arow0 = bi * 128, brow0 = bj * 128;
  int rgrp = lane >> 4, cl = lane & 15;
  int cidx[4], jst[4];
  float colsum[4] = {0.f, 0.f, 0.f, 0.f};
#pragma unroll
  for (int nj = 0; nj < 4; nj++) {
    cidx[nj] = brow0 + wc * 64 + nj * 16 + cl;
    jst[nj] = first_occ[y[cidx[nj]]];
  }
#pragma unroll
  for (int mi = 0; mi < 4; mi++) {
    int rb = arow0 + wr * 64 + mi * 16 + rgrp * 4;
#pragma unroll
    for (int reg = 0; reg < 4; reg++) {
      int r = rb + reg;
      float rs = 0.f;
#pragma unroll
      for (int nj = 0; nj < 4; nj++) {
        float v = acc[mi][nj][reg];
        float e = exp2f(v * c2);
        rs += e;
        colsum[nj] += e;
        if (jst[nj] == r) posdot[cidx[nj]] = v;   // unique position per column
      }
#pragma unroll
      for (int m = 1; m <= 8; m <<= 1) rs += __shfl_xor(rs, m);  // over 16 col-lanes
      if (cl == 0) atomicAdd(&total[r], rs);
    }
  }
  if (bi != bj) {   // off-diagonal: column sums are the mirrored rows' contributions
#pragma unroll
    for (int nj = 0; nj < 4; nj++) {
      float cs = colsum[nj];
      cs += __shfl_xor(cs, 16);
      cs += __shfl_xor(cs, 32);
      if (lane < 16) atomicAdd(&total[cidx[nj]], cs);
    }
  }
}

// ---- final reduction ----
__global__ void finalize_kernel(const float* __restrict__ total, const float* __restrict__ posdot,
                                const float* __restrict__ celogp, float* __restrict__ out) {
  int t = threadIdx.x;  // 1024 threads
  float fs = 0.f, cs = 0.f;
  for (int i = t; i < Bn; i += 1024) {
    fs += logf(total[i]) - 2.0f * posdot[i];
    cs += celogp[i];
  }
  fs = wsum(fs);
  cs = wsum(cs);
  __shared__ float rf[16], rc[16];
  if ((t & 63) == 0) { rf[t >> 6] = fs; rc[t >> 6] = cs; }
  __syncthreads();
  if (t == 0) {
    float lf = 0.f, la = 0.f;
#pragma unroll
    for (int w = 0; w < 16; w++) { lf += rf[w]; la += rc[w]; }
    lf /= (float)Bn;
    la /= (float)Bn;
    out[0] = la + 0.05f * lf;
    out[1] = la;
    out[2] = lf;
  }
}

extern "C" void kernel_launch(void* const* d_in, const int* in_sizes, int n_in,
                              void* d_out, int out_size, void* d_ws, size_t ws_size,
                              hipStream_t stream) {
  const float* data = (const float*)d_in[0];
  const float* x = (const float*)d_in[1];
  const int* y = (const int*)d_in[2];
  char* ws = (char*)d_ws;
  unsigned short* xn = (unsigned short*)ws;                       // 8 MB bf16, blocked layout
  float* total = (float*)(ws + (size_t)8 * 1024 * 1024);          // 16 KB
  float* posdot = total + Bn;                                     // 16 KB
  float* celogp = posdot + Bn;                                    // 16 KB
  int* first_occ = (int*)(celogp + Bn);                           // 4 KB
  float* out = (float*)d_out;

  hipLaunchKernelGGL(prep_kernel, dim3(2 * Bn), dim3(256), 0, stream,
                     data, x, y, xn, celogp, total, first_occ);
  hipLaunchKernelGGL(firstocc_kernel, dim3(16), dim3(256), 0, stream, y, first_occ);
  hipLaunchKernelGGL(gemm_expsum_kernel, dim3(NPANEL * (NPANEL + 1) / 2), dim3(256), 0, stream,
                     (const __bf16*)xn, y, first_occ, total, posdot);
  hipLaunchKernelGGL(finalize_kernel, dim3(1), dim3(1024), 0, stream, total, posdot, celogp, out);
}